// Round 4
// baseline (922.308 us; speedup 1.0000x reference)
//
#include <hip/hip_runtime.h>
#include <cstdint>
#include <cstddef>

// ---------------------------------------------------------------------------
// MaxK-GIN: h=relu(x@W_in+b); 2x { h=h@W+b; maxk16; neigh=sum_in(h_sparse);
//           h=(1+eps)*h_sparse+neigh }; out = h@W_out+b_out
// GEMMs: split-bf16 (hi+lo) MFMA, persistent-W blocks (stage once, no
// per-tile barriers). Aggregation: dst-CSR + LDS gather, packed (val,idx)
// pairs, 8 edges in flight per wave.
// ---------------------------------------------------------------------------

typedef __attribute__((ext_vector_type(8))) short bf16x8;
typedef __attribute__((ext_vector_type(4))) float f32x4;

__device__ __forceinline__ unsigned rne_bf16(float v) {
  unsigned u = __float_as_uint(v);
  return (u + 0x7fffu + ((u >> 16) & 1u)) >> 16;
}

// ---------------- fused W^T build: all 4 weights -> hi/lo bf16 --------------
// out layout (shorts): region bases 0 / 32768 / 65536 / 98304.
// each region: H[n*128] then L[n*128].
__global__ __launch_bounds__(256) void wt_build_all_kernel(
    const float* __restrict__ W_in, const float* __restrict__ W_lin,
    const float* __restrict__ W_out, short* __restrict__ out) {
  const int i = blockIdx.x * 256 + threadIdx.x;
  if (i >= 57344) return;
  const float* W;
  int nout, local;
  short* H;
  if (i < 16384) {
    W = W_in; nout = 128; local = i; H = out;
  } else if (i < 32768) {
    W = W_lin; nout = 128; local = i - 16384; H = out + 32768;
  } else if (i < 49152) {
    W = W_lin + 16384; nout = 128; local = i - 32768; H = out + 65536;
  } else {
    W = W_out; nout = 64; local = i - 49152; H = out + 98304;
  }
  const int nn = local >> 7, k = local & 127;
  const float v = W[k * nout + nn];
  const unsigned hb = rne_bf16(v);
  const float hf = __uint_as_float(hb << 16);
  const unsigned lb = rne_bf16(v - hf);
  H[local] = (short)hb;
  H[local + nout * 128] = (short)lb;
}

// ---------------- MFMA GEMM: Y = X[.,128] @ W + bias (opt relu) -------------
// persistent-W: stage W^T hi/lo once, then grid-stride row tiles, no barriers.
template <int NOUT, bool RELU>
__global__ __launch_bounds__(256, 2) void mfma_gemm_kernel(
    const float* __restrict__ X, const short* __restrict__ WtH,
    const short* __restrict__ WtL, const float* __restrict__ bias,
    float* __restrict__ Y, int nrows, int ntiles) {
  constexpr int NT = NOUT / 16;
  constexpr int LDB = 128 * 2 + 16;  // bytes per row, +16B pad (2-way, free)
  constexpr int PLANE = NOUT * LDB;
  __shared__ char lds[2 * PLANE];

  const int tid = threadIdx.x;
  for (int u = tid; u < 2 * NOUT * 16; u += 256) {
    const int plane = u / (NOUT * 16);
    const int v = u % (NOUT * 16);
    const int nrow = v >> 4, seg = v & 15;
    const short* src = plane ? WtL : WtH;
    const float4 d = *(const float4*)&src[nrow * 128 + seg * 8];
    *(float4*)&lds[plane * PLANE + nrow * LDB + seg * 16] = d;
  }
  __syncthreads();  // only barrier; LDS read-only afterwards

  const int lane = tid & 63;
  const int wv = tid >> 6;
  const int li = lane & 15;
  const int kg = lane >> 4;

  float bv[NT];
#pragma unroll
  for (int t = 0; t < NT; ++t) bv[t] = bias[t * 16 + li];

  for (int tile = blockIdx.x; tile < ntiles; tile += gridDim.x) {
    const int row = tile * 64 + wv * 16 + li;
    const int rowc = (row < nrows) ? row : (nrows - 1);
    const float* xrow = X + (size_t)rowc * 128;

    f32x4 acc[NT];
#pragma unroll
    for (int t = 0; t < NT; ++t) acc[t] = (f32x4){0.f, 0.f, 0.f, 0.f};

#pragma unroll
    for (int c = 0; c < 4; ++c) {
      const float4 p0 = *(const float4*)&xrow[c * 32 + kg * 8];
      const float4 p1 = *(const float4*)&xrow[c * 32 + kg * 8 + 4];
      float f[8] = {p0.x, p0.y, p0.z, p0.w, p1.x, p1.y, p1.z, p1.w};
      bf16x8 ah, al;
#pragma unroll
      for (int e = 0; e < 8; ++e) {
        const unsigned hb = rne_bf16(f[e]);
        const float hf = __uint_as_float(hb << 16);
        const unsigned lb = rne_bf16(f[e] - hf);
        ah[e] = (short)hb;
        al[e] = (short)lb;
      }
      const int kb = c * 64 + kg * 16;
#pragma unroll
      for (int t = 0; t < NT; ++t) {
        const int boff = (t * 16 + li) * LDB + kb;
        const bf16x8 bh = *(const bf16x8*)&lds[boff];
        const bf16x8 bl = *(const bf16x8*)&lds[PLANE + boff];
        acc[t] = __builtin_amdgcn_mfma_f32_16x16x32_bf16(al, bh, acc[t], 0, 0, 0);
        acc[t] = __builtin_amdgcn_mfma_f32_16x16x32_bf16(ah, bl, acc[t], 0, 0, 0);
        acc[t] = __builtin_amdgcn_mfma_f32_16x16x32_bf16(ah, bh, acc[t], 0, 0, 0);
      }
    }

    // D layout: col = lane&15, row = (lane>>4)*4 + reg
    const int orow = tile * 64 + wv * 16 + kg * 4;
#pragma unroll
    for (int t = 0; t < NT; ++t) {
      const int col = t * 16 + li;
#pragma unroll
      for (int r = 0; r < 4; ++r) {
        const int rr = orow + r;
        if (rr < nrows) {
          float o = acc[t][r] + bv[t];
          if (RELU) o = fmaxf(o, 0.f);
          Y[(size_t)rr * NOUT + col] = o;
        }
      }
    }
  }
}

// ---------------- MaxK: top-16 of 128 per row -> packed (val, idx) ----------
__global__ __launch_bounds__(256) void maxk_kernel(
    const float* __restrict__ T, float2* __restrict__ pairs, int nrows) {
  const int lane = threadIdx.x & 63;
  const int wid = threadIdx.x >> 6;

  for (int row = blockIdx.x * 4 + wid; row < nrows; row += gridDim.x * 4) {
    float v0 = T[(size_t)row * 128 + lane];
    float v1 = T[(size_t)row * 128 + 64 + lane];

#pragma unroll
    for (int it = 0; it < 16; ++it) {
      float m = fmaxf(v0, v1);
#pragma unroll
      for (int off = 32; off; off >>= 1) m = fmaxf(m, __shfl_xor(m, off));
      const unsigned long long b0 = __ballot(v0 == m);
      int sel;
      if (b0) {
        sel = __ffsll(b0) - 1;
        if (lane == sel) v0 = -INFINITY;
      } else {
        const unsigned long long b1 = __ballot(v1 == m);
        sel = __ffsll(b1) - 1;
        if (lane == sel) v1 = -INFINITY;
        sel += 64;
      }
      if (lane == 0) {
        pairs[(size_t)row * 16 + it] = make_float2(m, __int_as_float(sel));
      }
    }
  }
}

// ---------------- CSR build ------------------------------------------------
__global__ __launch_bounds__(256) void hist_kernel(const int* __restrict__ dst,
                                                   int* __restrict__ deg,
                                                   int E) {
  const int e = blockIdx.x * 256 + threadIdx.x;
  if (e < E) atomicAdd(&deg[dst[e]], 1);
}

__global__ __launch_bounds__(256) void scan1_kernel(
    const int* __restrict__ deg, int* __restrict__ out,
    int* __restrict__ bsums, int n) {
  __shared__ int wsum[4];
  const int t = threadIdx.x;
  const int base = blockIdx.x * 1024 + t * 4;
  int d0 = 0, d1 = 0, d2 = 0, d3 = 0;
  if (base + 0 < n) d0 = deg[base + 0];
  if (base + 1 < n) d1 = deg[base + 1];
  if (base + 2 < n) d2 = deg[base + 2];
  if (base + 3 < n) d3 = deg[base + 3];
  const int s = d0 + d1 + d2 + d3;
  const int lane = t & 63, wid = t >> 6;
  int incl = s;
#pragma unroll
  for (int off = 1; off < 64; off <<= 1) {
    int u = __shfl_up(incl, off);
    if (lane >= off) incl += u;
  }
  if (lane == 63) wsum[wid] = incl;
  __syncthreads();
  int woff = 0;
  for (int w = 0; w < wid; ++w) woff += wsum[w];
  const int excl = woff + incl - s;
  if (base + 0 < n) out[base + 0] = excl;
  if (base + 1 < n) out[base + 1] = excl + d0;
  if (base + 2 < n) out[base + 2] = excl + d0 + d1;
  if (base + 3 < n) out[base + 3] = excl + d0 + d1 + d2;
  if (t == 255) bsums[blockIdx.x] = woff + incl;
}

// single-wave scan over block sums (nb <= 128)
__global__ __launch_bounds__(64) void scan2_kernel(int* __restrict__ bsums,
                                                   int nb) {
  const int lane = threadIdx.x;
  const int a = (lane < nb) ? bsums[lane] : 0;
  const int b = (lane + 64 < nb) ? bsums[lane + 64] : 0;
  int ia = a, ib = b;
#pragma unroll
  for (int off = 1; off < 64; off <<= 1) {
    const int ta = __shfl_up(ia, off);
    const int tb = __shfl_up(ib, off);
    if (lane >= off) { ia += ta; ib += tb; }
  }
  const int totA = __shfl(ia, 63);
  if (lane < nb) bsums[lane] = ia - a;
  if (lane + 64 < nb) bsums[lane + 64] = totA + ib - b;
}

__global__ __launch_bounds__(256) void scan3_kernel(
    int* __restrict__ rs, int* __restrict__ cursor,
    const int* __restrict__ bsums, int n, int E) {
  const int i = blockIdx.x * 256 + threadIdx.x;
  if (i < n) {
    const int v = rs[i] + bsums[i >> 10];
    rs[i] = v;
    cursor[i] = v;
  }
  if (i == n) rs[n] = E;
}

__global__ __launch_bounds__(256) void fill_kernel(
    const int* __restrict__ src, const int* __restrict__ dst,
    int* __restrict__ cursor, int* __restrict__ csr_src, int E) {
  const int e = blockIdx.x * 256 + threadIdx.x;
  if (e < E) {
    const int pos = atomicAdd(&cursor[dst[e]], 1);
    csr_src[pos] = src[e];
  }
}

// ---------------- Gather: H[d] = (1+eps)*sparse[d] + sum_in sparse[src] -----
// wave per dst row; 64 edge srcs cached in reg; 8 edges in flight;
// packed pairs -> one float4 load per lane covers 2 nnz.
__global__ __launch_bounds__(256) void gather_kernel(
    const int* __restrict__ rs, const int* __restrict__ csr_src,
    const float2* __restrict__ pairs, const float* __restrict__ eps_p,
    float* __restrict__ H, int nrows) {
  __shared__ float rowbuf[4][128];
  const int lane = threadIdx.x & 63;
  const int wid = threadIdx.x >> 6;
  const float e1 = 1.0f + *eps_p;
  float* row = rowbuf[wid];

  const int r = blockIdx.x * 4 + wid;
  if (r >= nrows) return;

  row[lane] = 0.f;
  row[lane + 64] = 0.f;

  const int beg = rs[r], end = rs[r + 1];
  const int sub = lane >> 3;       // which of 8 concurrent edges
  const int p2 = (lane & 7) * 2;   // this lane's 2 nnz pairs

  for (int base = beg; base < end; base += 64) {
    const int cnt = min(64, end - base);
    const int es = (lane < cnt) ? csr_src[base + lane] : 0;
    for (int it = 0; it < cnt; it += 8) {
      const int s = __shfl(es, it + sub);
      if (it + sub < cnt) {
        const float4 pv = *(const float4*)&pairs[(size_t)s * 16 + p2];
        atomicAdd(&row[__float_as_int(pv.y)], pv.x);
        atomicAdd(&row[__float_as_int(pv.w)], pv.z);
      }
    }
  }
  if (lane < 16) {
    const float2 pv = pairs[(size_t)r * 16 + lane];
    atomicAdd(&row[__float_as_int(pv.y)], e1 * pv.x);
  }
  // same-wave DS ops are in-order
  H[(size_t)r * 128 + lane] = row[lane];
  H[(size_t)r * 128 + 64 + lane] = row[lane + 64];
}

// ---------------------------------------------------------------------------
extern "C" void kernel_launch(void* const* d_in, const int* in_sizes, int n_in,
                              void* d_out, int out_size, void* d_ws,
                              size_t ws_size, hipStream_t stream) {
  const float* x = (const float*)d_in[0];
  const int* src = (const int*)d_in[1];
  const int* dst = (const int*)d_in[2];
  const float* W_in = (const float*)d_in[3];
  const float* b_in = (const float*)d_in[4];
  const float* W_lin = (const float*)d_in[5];
  const float* b_lin = (const float*)d_in[6];
  const float* eps = (const float*)d_in[7];
  const float* W_out = (const float*)d_in[8];
  const float* b_out = (const float*)d_in[9];
  float* out = (float*)d_out;

  const int n = in_sizes[0] / 128;
  const int E = in_sizes[1];

  char* w = (char*)d_ws;
  float* A = (float*)w;               w += (size_t)n * 128 * 4;
  float* B = (float*)w;               w += (size_t)n * 128 * 4;
  float2* pairs = (float2*)w;         w += (size_t)n * 16 * 8;
  int* deg = (int*)w;                 w += (size_t)n * 4;
  int* rs = (int*)w;                  w += (size_t)(n + 1) * 4;
  int* cursor = (int*)w;              w += (size_t)n * 4;
  int* bsums = (int*)w;               w += 1024 * 4;
  int* csr_src = (int*)w;             w += (size_t)E * 4;
  short* wtAll = (short*)w;           w += (size_t)114688 * 2;

  short* wtIn = wtAll;            // H at +0, L at +16384
  short* wtL0 = wtAll + 32768;
  short* wtL1 = wtAll + 65536;
  short* wtOut = wtAll + 98304;   // H at +0, L at +8192

  const int nb = (n + 1023) / 1024;
  const int gtiles = (n + 63) / 64;
  const int ggrid = (gtiles < 512) ? gtiles : 512;
  const dim3 blk(256);

  // ---- CSR build ----
  hipMemsetAsync(deg, 0, (size_t)n * 4, stream);
  hist_kernel<<<(E + 255) / 256, blk, 0, stream>>>(dst, deg, E);
  scan1_kernel<<<nb, blk, 0, stream>>>(deg, rs, bsums, n);
  scan2_kernel<<<1, 64, 0, stream>>>(bsums, nb);
  scan3_kernel<<<(n + 256) / 256, blk, 0, stream>>>(rs, cursor, bsums, n, E);
  fill_kernel<<<(E + 255) / 256, blk, 0, stream>>>(src, dst, cursor, csr_src, E);

  // ---- weights -> hi/lo bf16 (one kernel) ----
  wt_build_all_kernel<<<(57344 + 255) / 256, blk, 0, stream>>>(W_in, W_lin,
                                                               W_out, wtAll);

  // ---- h = relu(x @ W_in + b_in) ----
  mfma_gemm_kernel<128, true><<<ggrid, blk, 0, stream>>>(
      x, wtIn, wtIn + 16384, b_in, A, n, gtiles);

  for (int l = 0; l < 2; ++l) {
    short* wt = l ? wtL1 : wtL0;
    mfma_gemm_kernel<128, false><<<ggrid, blk, 0, stream>>>(
        A, wt, wt + 16384, b_lin + (size_t)l * 128, B, n, gtiles);
    maxk_kernel<<<2048, blk, 0, stream>>>(B, pairs, n);
    gather_kernel<<<(n + 3) / 4, blk, 0, stream>>>(rs, csr_src, pairs, eps + l,
                                                   A, n);
  }

  mfma_gemm_kernel<64, false><<<ggrid, blk, 0, stream>>>(
      A, wtOut, wtOut + 8192, b_out, out, n, gtiles);
}